// Round 2
// baseline (849.875 us; speedup 1.0000x reference)
//
#include <hip/hip_runtime.h>
#include <cfloat>
#include <cmath>
#include <stdint.h>

#define N 8192
#define D 512
#define K 16
#define RB 128     // rows per k_knn block
#define JS 1024    // cols per slice (8 slices)
#define NSL (N / JS)
#define JT 128     // j-tile width
#define KC 64      // k chunk
#define NCH (D / KC)
#define CAP 16     // survivor slots per row per pass

typedef __bf16 bf16x8 __attribute__((ext_vector_type(8)));
typedef __bf16 bf16x4 __attribute__((ext_vector_type(4)));
typedef float  f32x16 __attribute__((ext_vector_type(16)));
typedef float  f32x4  __attribute__((ext_vector_type(4)));

// ---------------- kernel 1: cast to bf16 + row squared norms (fp32) ----------
__global__ __launch_bounds__(256)
void k_cast_sqnorm(const float* __restrict__ emb, float* __restrict__ sq,
                   __bf16* __restrict__ embh) {
    int row = blockIdx.x * 4 + (threadIdx.x >> 6);
    int lane = threadIdx.x & 63;
    const float4* e = (const float4*)(emb + (size_t)row * D);
    float s = 0.f;
    #pragma unroll
    for (int c = 0; c < 2; c++) {
        float4 v = e[lane + 64 * c];
        s += v.x * v.x + v.y * v.y + v.z * v.z + v.w * v.w;
        bf16x4 h = { (__bf16)v.x, (__bf16)v.y, (__bf16)v.z, (__bf16)v.w };
        *(bf16x4*)&embh[(size_t)row * D + (size_t)(lane + 64 * c) * 4] = h;
    }
    for (int off = 32; off; off >>= 1) s += __shfl_down(s, off, 64);
    if (lane == 0) sq[row] = s;
}

// ---------------- kernel 2: MFMA distance GEMM + streaming top-16 ------------
// grid 512: rg = bid>>3 (128 rows), sl = bid&7 (1024-col slice).
// 4 waves, wave tile 64x64 = 4 x mfma_32x32x16_bf16 accumulators.
// LDS ~71.7 KB -> 2 blocks/CU. NO min-waves launch_bounds: the (256,2) hint
// in the previous round capped arch-VGPRs at 124 and spilled acc/prefetch to
// scratch (423 MB WRITE_SIZE). Without the hint the compiler uses ~156 arch
// VGPRs (+64 acc), still within the 256-register class => 2 waves/SIMD, and
// LDS (72 KB) allows the 2 blocks/CU we want.
__global__ __launch_bounds__(256)
void k_knn(const __bf16* __restrict__ embh, const float* __restrict__ sq,
           float* __restrict__ pd2, int* __restrict__ pidx) {
    __shared__ __align__(16) __bf16 As[RB][KC + 8];
    __shared__ __align__(16) __bf16 Bs[JT][KC + 8];
    __shared__ float svD[RB][CAP];
    __shared__ int   svI[RB][CAP];
    __shared__ float listD[RB][K];
    __shared__ int   listI[RB][K];
    __shared__ float sqr[RB];
    __shared__ float kadj[RB];    // kmax - sq[row]  (filter threshold on sqj-2*dot)
    __shared__ float kmaxA[RB];
    __shared__ int   scount[RB];
    __shared__ int   again;

    const int t   = threadIdx.x;
    const int rg  = blockIdx.x >> 3;
    const int sl  = blockIdx.x & 7;
    const int ib  = rg * RB;
    const int jsb = sl * JS;
    const int lane = t & 63, quad = lane >> 5, l31 = lane & 31;
    const int w  = t >> 6;
    const int wr = (w >> 1) * 64;
    const int wc = (w & 1) * 64;

    if (t < RB) {
        sqr[t] = sq[ib + t];
        kadj[t] = FLT_MAX; kmaxA[t] = FLT_MAX; scount[t] = 0;
        #pragma unroll
        for (int q = 0; q < K; q++) { listD[t][q] = FLT_MAX; listI[t][q] = 0; }
    }
    __syncthreads();

    for (int jt = 0; jt < JS / JT; jt++) {
        const int jb = jsb + jt * JT;
        f32x16 zero = {};
        f32x16 acc[2][2];
        acc[0][0] = zero; acc[0][1] = zero; acc[1][0] = zero; acc[1][1] = zero;

        // stage chunk 0
        #pragma unroll
        for (int q = 0; q < 4; q++) {
            int s = t + 256 * q;           // 0..1023
            int row = s >> 3, g = s & 7;   // 128 rows x 8 granules of 8 bf16
            *(uint4*)&As[row][g * 8] = *(const uint4*)&embh[(size_t)(ib + row) * D + g * 8];
            *(uint4*)&Bs[row][g * 8] = *(const uint4*)&embh[(size_t)(jb + row) * D + g * 8];
        }
        __syncthreads();

        uint4 pfA[4], pfB[4];
        for (int kc = 0; kc < NCH; kc++) {
            if (kc + 1 < NCH) {            // register prefetch of next chunk
                int k0 = (kc + 1) * KC;
                #pragma unroll
                for (int q = 0; q < 4; q++) {
                    int s = t + 256 * q; int row = s >> 3, g = s & 7;
                    pfA[q] = *(const uint4*)&embh[(size_t)(ib + row) * D + k0 + g * 8];
                    pfB[q] = *(const uint4*)&embh[(size_t)(jb + row) * D + k0 + g * 8];
                }
            }
            #pragma unroll
            for (int kk = 0; kk < KC / 16; kk++) {
                int ko = kk * 16 + quad * 8;
                bf16x8 a0 = *(const bf16x8*)&As[wr + l31][ko];
                bf16x8 a1 = *(const bf16x8*)&As[wr + 32 + l31][ko];
                bf16x8 b0 = *(const bf16x8*)&Bs[wc + l31][ko];
                bf16x8 b1 = *(const bf16x8*)&Bs[wc + 32 + l31][ko];
                acc[0][0] = __builtin_amdgcn_mfma_f32_32x32x16_bf16(a0, b0, acc[0][0], 0, 0, 0);
                acc[0][1] = __builtin_amdgcn_mfma_f32_32x32x16_bf16(a0, b1, acc[0][1], 0, 0, 0);
                acc[1][0] = __builtin_amdgcn_mfma_f32_32x32x16_bf16(a1, b0, acc[1][0], 0, 0, 0);
                acc[1][1] = __builtin_amdgcn_mfma_f32_32x32x16_bf16(a1, b1, acc[1][1], 0, 0, 0);
            }
            __syncthreads();               // all waves done reading As/Bs
            if (kc + 1 < NCH) {
                #pragma unroll
                for (int q = 0; q < 4; q++) {
                    int s = t + 256 * q; int row = s >> 3, g = s & 7;
                    *(uint4*)&As[row][g * 8] = pfA[q];
                    *(uint4*)&Bs[row][g * 8] = pfB[q];
                }
            }
            __syncthreads();               // next chunk visible
        }

        // ---- selection: capped survivor buffer + dedupe mask + retry ----
        float sqc0 = sq[jb + wc + l31];
        float sqc1 = sq[jb + wc + 32 + l31];
        uint64_t mask = 0;
        while (true) {
            if (t == 0) again = 0;
            #pragma unroll
            for (int r = 0; r < 2; r++)
            #pragma unroll
            for (int c = 0; c < 2; c++)
            #pragma unroll
            for (int reg = 0; reg < 16; reg++) {
                int bit = ((r * 2 + c) << 4) | reg;
                if ((mask >> bit) & 1) continue;
                int row_l = wr + r * 32 + ((reg & 3) + ((reg >> 2) << 3) + (quad << 2));
                float t2 = (c ? sqc1 : sqc0) - 2.f * acc[r][c][reg];
                if (t2 < kadj[row_l]) {
                    int j = jb + wc + c * 32 + l31;
                    if (j != ib + row_l) {
                        int p = atomicAdd(&scount[row_l], 1);
                        if (p < CAP) {
                            svD[row_l][p] = t2 + sqr[row_l];
                            svI[row_l][p] = j;
                            mask |= (1ull << bit);
                        }
                    }
                }
            }
            __syncthreads();
            if (t < RB) {
                int cnt = scount[t];
                if (cnt) {
                    int m = cnt < CAP ? cnt : CAP;
                    float kmx = kmaxA[t];
                    for (int p = 0; p < m; p++) {
                        float d2 = svD[t][p];
                        if (d2 < kmx) {
                            int am = 0; float mx = listD[t][0];
                            #pragma unroll
                            for (int q = 1; q < K; q++)
                                if (listD[t][q] > mx) { mx = listD[t][q]; am = q; }
                            listD[t][am] = d2; listI[t][am] = svI[t][p];
                            mx = listD[t][0];
                            #pragma unroll
                            for (int q = 1; q < K; q++) mx = fmaxf(mx, listD[t][q]);
                            kmx = mx;
                        }
                    }
                    kmaxA[t] = kmx; kadj[t] = kmx - sqr[t];
                    scount[t] = 0;
                    if (cnt > CAP) again = 1;
                }
            }
            __syncthreads();
            int more = again;
            __syncthreads();
            if (!more) break;
        }
    }

    if (t < RB) {
        #pragma unroll
        for (int q = 0; q < K; q++) {
            pd2[(size_t)(ib + t) * (NSL * K) + sl * K + q]  = listD[t][q];
            pidx[(size_t)(ib + t) * (NSL * K) + sl * K + q] = listI[t][q];
        }
    }
}

// ---------------- kernel 3: merge 8 partial lists per row --------------------
__global__ __launch_bounds__(256)
void k_merge(const float* __restrict__ pd2, const int* __restrict__ pidx,
             int* __restrict__ knn, float* __restrict__ row_sum) {
    int row = blockIdx.x * 256 + threadIdx.x;
    float bd[K]; int bi[K];
    #pragma unroll
    for (int q = 0; q < K; q++) { bd[q] = FLT_MAX; bi[q] = 0; }
    float kmx = FLT_MAX;
    const float* pr = pd2 + (size_t)row * (NSL * K);
    const int*   pi = pidx + (size_t)row * (NSL * K);
    for (int s = 0; s < NSL * K; s++) {
        float d2 = pr[s];
        if (d2 < kmx) {
            int am = 0; float mx = bd[0];
            #pragma unroll
            for (int q = 1; q < K; q++) if (bd[q] > mx) { mx = bd[q]; am = q; }
            bd[am] = d2; bi[am] = pi[s];
            mx = bd[0];
            #pragma unroll
            for (int q = 1; q < K; q++) mx = fmaxf(mx, bd[q]);
            kmx = mx;
        }
    }
    float s = 0.f;
    #pragma unroll
    for (int q = 0; q < K; q++) {
        float d2 = bd[q];
        s += (d2 > 0.f) ? sqrtf(fmaxf(d2, 1e-12f)) : 0.f;
        knn[(size_t)row * K + q] = bi[q];
    }
    row_sum[row] = s;
}

// ---------------- kernel 4: per-row curvature via MFMA gram ------------------
// One wave per row i. Gram = Nb . Nb^T via mfma_f32_16x16x32_bf16 with the
// SAME fragment as A and B (both loaded [row][k]; the main GEMM validates this
// dual-layout A.B^T convention). 16 k-chunks of 32. acc layout: lane l holds
// gram[(l>>4)*4+q][l&15]. Diagonal broadcast via 16-float LDS per wave, then
// each lane forms its 4 inter-distances; sum over all ordered pairs = 2x the
// j<l sum.
__global__ __launch_bounds__(256)
void k_curv(const __bf16* __restrict__ embh, const int* __restrict__ knn_idx,
            const float* __restrict__ row_sum, const float* __restrict__ ref_curv,
            float* __restrict__ curv_err) {
    __shared__ float diagS[4][16];
    const int t = threadIdx.x;
    const int w = t >> 6, lane = t & 63;
    const int i = blockIdx.x * 4 + w;

    const int nidx = knn_idx[(size_t)i * K + (lane & 15)];
    const __bf16* src = embh + (size_t)nidx * D + (lane >> 4) * 8;

    f32x4 acc = {};
    #pragma unroll
    for (int kc = 0; kc < D / 32; kc++) {
        bf16x8 a = *(const bf16x8*)(src + kc * 32);
        acc = __builtin_amdgcn_mfma_f32_16x16x32_bf16(a, a, acc, 0, 0, 0);
    }

    // write diagonal entries gram[c][c]
    #pragma unroll
    for (int q = 0; q < 4; q++) {
        int r = (lane >> 4) * 4 + q;
        if (r == (lane & 15)) diagS[w][r] = acc[q];
    }
    __syncthreads();

    float s = 0.f;
    #pragma unroll
    for (int q = 0; q < 4; q++) {
        int r = (lane >> 4) * 4 + q, c = lane & 15;
        if (r != c) {
            float d2 = diagS[w][r] + diagS[w][c] - 2.f * acc[q];
            s += (d2 > 0.f) ? sqrtf(fmaxf(d2, 1e-12f)) : 0.f;
        }
    }
    #pragma unroll
    for (int off = 32; off; off >>= 1) s += __shfl_down(s, off, 64);

    if (lane == 0) {
        float inter_mean = (0.5f * s) / 120.f;
        float avg = row_sum[i] / 16.f;
        float curv = inter_mean / (avg + 1e-8f);
        float diff = curv - ref_curv[i];
        curv_err[i] = diff * diff;
    }
}

// ---------------- kernel 5: final scalar reduce ------------------------------
__global__ __launch_bounds__(1024)
void k_final(const float* __restrict__ curv_err, const float* __restrict__ row_sum,
             const float* __restrict__ ref_dist, float* __restrict__ out) {
    const int t = threadIdx.x;
    float s1 = 0.f, s2 = 0.f, s3 = 0.f;
    for (int i = t; i < N; i += 1024) { s1 += curv_err[i]; s2 += row_sum[i]; }
    for (int i = t; i < N * K; i += 1024) s3 += ref_dist[i];
    for (int off = 32; off; off >>= 1) {
        s1 += __shfl_down(s1, off, 64);
        s2 += __shfl_down(s2, off, 64);
        s3 += __shfl_down(s3, off, 64);
    }
    __shared__ float a1[16], a2[16], a3[16];
    int w = t >> 6, lane = t & 63;
    if (lane == 0) { a1[w] = s1; a2[w] = s2; a3[w] = s3; }
    __syncthreads();
    if (t == 0) {
        float t1 = 0.f, t2 = 0.f, t3 = 0.f;
        for (int q = 0; q < 16; q++) { t1 += a1[q]; t2 += a2[q]; t3 += a3[q]; }
        float curv_loss = t1 / (float)N;
        float dm = t2 / (float)(N * K);
        float rm = t3 / (float)(N * K);
        float d = dm - rm;
        out[0] = curv_loss + 0.1f * d * d;
    }
}

extern "C" void kernel_launch(void* const* d_in, const int* in_sizes, int n_in,
                              void* d_out, int out_size, void* d_ws, size_t ws_size,
                              hipStream_t stream) {
    const float* emb      = (const float*)d_in[0];
    const float* ref_curv = (const float*)d_in[1];
    const float* ref_dist = (const float*)d_in[2];
    float* out = (float*)d_out;

    float*  sq       = (float*)d_ws;                         // N
    float*  row_sum  = sq + N;                               // N
    float*  curv_err = row_sum + N;                          // N
    float*  pd2      = curv_err + N;                         // N*128
    int*    pidx     = (int*)(pd2 + (size_t)N * NSL * K);    // N*128
    int*    knn      = pidx + (size_t)N * NSL * K;           // N*K
    __bf16* embh     = (__bf16*)(knn + (size_t)N * K);       // N*D bf16 (8 MB)

    k_cast_sqnorm<<<N / 4, 256, 0, stream>>>(emb, sq, embh);
    k_knn<<<(N / RB) * NSL, 256, 0, stream>>>(embh, sq, pd2, pidx);
    k_merge<<<N / 256, 256, 0, stream>>>(pd2, pidx, knn, row_sum);
    k_curv<<<N / 4, 256, 0, stream>>>(embh, knn, row_sum, ref_curv, curv_err);
    k_final<<<1, 1024, 0, stream>>>(curv_err, row_sum, ref_dist, out);
}

// Round 3
// 474.466 us; speedup vs baseline: 1.7912x; 1.7912x over previous
//
#include <hip/hip_runtime.h>
#include <cfloat>
#include <cmath>
#include <stdint.h>

#define N 8192
#define D 512
#define K 16
#define RB 128     // rows per k_knn block
#define JS 2048    // cols per slice (4 slices)  -- R0-proven, do NOT shrink (spill trap)
#define NSL (N / JS)
#define JT 128     // j-tile width
#define KC 64      // k chunk
#define NCH (D / KC)
#define CAP 32     // survivor slots per row per pass

typedef __bf16 bf16x8 __attribute__((ext_vector_type(8)));
typedef __bf16 bf16x4 __attribute__((ext_vector_type(4)));
typedef float  f32x16 __attribute__((ext_vector_type(16)));
typedef float  f32x4  __attribute__((ext_vector_type(4)));

// ---------------- kernel 1: cast to bf16 + row squared norms (fp32) ----------
__global__ __launch_bounds__(256)
void k_cast_sqnorm(const float* __restrict__ emb, float* __restrict__ sq,
                   __bf16* __restrict__ embh) {
    int row = blockIdx.x * 4 + (threadIdx.x >> 6);
    int lane = threadIdx.x & 63;
    const float4* e = (const float4*)(emb + (size_t)row * D);
    float s = 0.f;
    #pragma unroll
    for (int c = 0; c < 2; c++) {
        float4 v = e[lane + 64 * c];
        s += v.x * v.x + v.y * v.y + v.z * v.z + v.w * v.w;
        bf16x4 h = { (__bf16)v.x, (__bf16)v.y, (__bf16)v.z, (__bf16)v.w };
        *(bf16x4*)&embh[(size_t)row * D + (size_t)(lane + 64 * c) * 4] = h;
    }
    for (int off = 32; off; off >>= 1) s += __shfl_down(s, off, 64);
    if (lane == 0) sq[row] = s;
}

// ---------------- kernel 2: MFMA distance GEMM + streaming top-16 ------------
// grid 256: rg = bid>>2 (128 rows), sl = bid&3 (2048-col slice).
// R0 geometry (JS=2048, CAP=32, 121KB LDS, 1 block/CU) but with EIGHT waves:
// 512 threads, wave tile 32x64 (acc = 2 x f32x16, 32 VGPRs). 8 waves/CU = 2
// waves/SIMD doubles latency hiding in the MFMA and staging phases while
// *reducing* per-wave register pressure (~100 arch VGPRs — no spill headroom
// issues; R1/R2's JS=1024 variants spilled in every compile flavor).
__global__ __launch_bounds__(512)
void k_knn(const __bf16* __restrict__ embh, const float* __restrict__ sq,
           float* __restrict__ pd2, int* __restrict__ pidx) {
    __shared__ __align__(16) __bf16 As[RB][KC + 8];
    __shared__ __align__(16) __bf16 Bs[JT][KC + 8];
    __shared__ float svD[RB][CAP];
    __shared__ int   svI[RB][CAP];
    __shared__ float listD[RB][K];
    __shared__ int   listI[RB][K];
    __shared__ float sqr[RB];
    __shared__ float kadj[RB];    // kmax - sq[row]  (filter threshold on sqj-2*dot)
    __shared__ float kmaxA[RB];
    __shared__ int   scount[RB];
    __shared__ int   again;

    const int t   = threadIdx.x;
    const int rg  = blockIdx.x >> 2;
    const int sl  = blockIdx.x & 3;
    const int ib  = rg * RB;
    const int jsb = sl * JS;
    const int lane = t & 63, quad = lane >> 5, l31 = lane & 31;
    const int w  = t >> 6;            // 0..7
    const int wr = (w & 3) * 32;      // 4 row groups of 32
    const int wc = (w >> 2) * 64;     // 2 col groups of 64

    if (t < RB) {
        sqr[t] = sq[ib + t];
        kadj[t] = FLT_MAX; kmaxA[t] = FLT_MAX; scount[t] = 0;
        #pragma unroll
        for (int q = 0; q < K; q++) { listD[t][q] = FLT_MAX; listI[t][q] = 0; }
    }
    __syncthreads();

    for (int jt = 0; jt < JS / JT; jt++) {
        const int jb = jsb + jt * JT;
        f32x16 zero = {};
        f32x16 acc[2];
        acc[0] = zero; acc[1] = zero;

        // stage chunk 0: 1024 uint4 slots, 2 per thread
        #pragma unroll
        for (int q = 0; q < 2; q++) {
            int s = t + 512 * q;           // 0..1023
            int row = s >> 3, g = s & 7;   // 128 rows x 8 granules of 8 bf16
            *(uint4*)&As[row][g * 8] = *(const uint4*)&embh[(size_t)(ib + row) * D + g * 8];
            *(uint4*)&Bs[row][g * 8] = *(const uint4*)&embh[(size_t)(jb + row) * D + g * 8];
        }
        __syncthreads();

        uint4 pfA[2], pfB[2];
        for (int kc = 0; kc < NCH; kc++) {
            if (kc + 1 < NCH) {            // register prefetch of next chunk
                int k0 = (kc + 1) * KC;
                #pragma unroll
                for (int q = 0; q < 2; q++) {
                    int s = t + 512 * q; int row = s >> 3, g = s & 7;
                    pfA[q] = *(const uint4*)&embh[(size_t)(ib + row) * D + k0 + g * 8];
                    pfB[q] = *(const uint4*)&embh[(size_t)(jb + row) * D + k0 + g * 8];
                }
            }
            #pragma unroll
            for (int kk = 0; kk < KC / 16; kk++) {
                int ko = kk * 16 + quad * 8;
                bf16x8 a0 = *(const bf16x8*)&As[wr + l31][ko];
                bf16x8 b0 = *(const bf16x8*)&Bs[wc + l31][ko];
                bf16x8 b1 = *(const bf16x8*)&Bs[wc + 32 + l31][ko];
                acc[0] = __builtin_amdgcn_mfma_f32_32x32x16_bf16(a0, b0, acc[0], 0, 0, 0);
                acc[1] = __builtin_amdgcn_mfma_f32_32x32x16_bf16(a0, b1, acc[1], 0, 0, 0);
            }
            __syncthreads();               // all waves done reading As/Bs
            if (kc + 1 < NCH) {
                #pragma unroll
                for (int q = 0; q < 2; q++) {
                    int s = t + 512 * q; int row = s >> 3, g = s & 7;
                    *(uint4*)&As[row][g * 8] = pfA[q];
                    *(uint4*)&Bs[row][g * 8] = pfB[q];
                }
            }
            __syncthreads();               // next chunk visible
        }

        // ---- selection: capped survivor buffer + dedupe mask + retry ----
        float sqc0 = sq[jb + wc + l31];
        float sqc1 = sq[jb + wc + 32 + l31];
        uint32_t mask = 0;
        while (true) {
            if (t == 0) again = 0;
            #pragma unroll
            for (int c = 0; c < 2; c++)
            #pragma unroll
            for (int reg = 0; reg < 16; reg++) {
                int bit = (c << 4) | reg;
                if ((mask >> bit) & 1) continue;
                int row_l = wr + ((reg & 3) + ((reg >> 2) << 3) + (quad << 2));
                float t2 = (c ? sqc1 : sqc0) - 2.f * acc[c][reg];
                if (t2 < kadj[row_l]) {
                    int j = jb + wc + c * 32 + l31;
                    if (j != ib + row_l) {
                        int p = atomicAdd(&scount[row_l], 1);
                        if (p < CAP) {
                            svD[row_l][p] = t2 + sqr[row_l];
                            svI[row_l][p] = j;
                            mask |= (1u << bit);
                        }
                    }
                }
            }
            __syncthreads();
            if (t < RB) {
                int cnt = scount[t];
                if (cnt) {
                    int m = cnt < CAP ? cnt : CAP;
                    float kmx = kmaxA[t];
                    for (int p = 0; p < m; p++) {
                        float d2 = svD[t][p];
                        if (d2 < kmx) {
                            int am = 0; float mx = listD[t][0];
                            #pragma unroll
                            for (int q = 1; q < K; q++)
                                if (listD[t][q] > mx) { mx = listD[t][q]; am = q; }
                            listD[t][am] = d2; listI[t][am] = svI[t][p];
                            mx = listD[t][0];
                            #pragma unroll
                            for (int q = 1; q < K; q++) mx = fmaxf(mx, listD[t][q]);
                            kmx = mx;
                        }
                    }
                    kmaxA[t] = kmx; kadj[t] = kmx - sqr[t];
                    scount[t] = 0;
                    if (cnt > CAP) again = 1;
                }
            }
            __syncthreads();
            int more = again;
            __syncthreads();
            if (!more) break;
        }
    }

    if (t < RB) {
        #pragma unroll
        for (int q = 0; q < K; q++) {
            pd2[(size_t)(ib + t) * (NSL * K) + sl * K + q]  = listD[t][q];
            pidx[(size_t)(ib + t) * (NSL * K) + sl * K + q] = listI[t][q];
        }
    }
}

// ---------------- kernel 3: merge 4 partial lists per row --------------------
__global__ __launch_bounds__(256)
void k_merge(const float* __restrict__ pd2, const int* __restrict__ pidx,
             int* __restrict__ knn, float* __restrict__ row_sum) {
    int row = blockIdx.x * 256 + threadIdx.x;
    float bd[K]; int bi[K];
    #pragma unroll
    for (int q = 0; q < K; q++) { bd[q] = FLT_MAX; bi[q] = 0; }
    float kmx = FLT_MAX;
    const float* pr = pd2 + (size_t)row * (NSL * K);
    const int*   pi = pidx + (size_t)row * (NSL * K);
    for (int s = 0; s < NSL * K; s++) {
        float d2 = pr[s];
        if (d2 < kmx) {
            int am = 0; float mx = bd[0];
            #pragma unroll
            for (int q = 1; q < K; q++) if (bd[q] > mx) { mx = bd[q]; am = q; }
            bd[am] = d2; bi[am] = pi[s];
            mx = bd[0];
            #pragma unroll
            for (int q = 1; q < K; q++) mx = fmaxf(mx, bd[q]);
            kmx = mx;
        }
    }
    float s = 0.f;
    #pragma unroll
    for (int q = 0; q < K; q++) {
        float d2 = bd[q];
        s += (d2 > 0.f) ? sqrtf(fmaxf(d2, 1e-12f)) : 0.f;
        knn[(size_t)row * K + q] = bi[q];
    }
    row_sum[row] = s;
}

// ---------------- kernel 4: per-row curvature via MFMA gram ------------------
// One wave per row i. Gram = Nb . Nb^T via mfma_f32_16x16x32_bf16 with the
// SAME fragment as A and B. Verified exact (absmax 0.0) in round 2.
__global__ __launch_bounds__(256)
void k_curv(const __bf16* __restrict__ embh, const int* __restrict__ knn_idx,
            const float* __restrict__ row_sum, const float* __restrict__ ref_curv,
            float* __restrict__ curv_err) {
    __shared__ float diagS[4][16];
    const int t = threadIdx.x;
    const int w = t >> 6, lane = t & 63;
    const int i = blockIdx.x * 4 + w;

    const int nidx = knn_idx[(size_t)i * K + (lane & 15)];
    const __bf16* src = embh + (size_t)nidx * D + (lane >> 4) * 8;

    f32x4 acc = {};
    #pragma unroll
    for (int kc = 0; kc < D / 32; kc++) {
        bf16x8 a = *(const bf16x8*)(src + kc * 32);
        acc = __builtin_amdgcn_mfma_f32_16x16x32_bf16(a, a, acc, 0, 0, 0);
    }

    // write diagonal entries gram[c][c]
    #pragma unroll
    for (int q = 0; q < 4; q++) {
        int r = (lane >> 4) * 4 + q;
        if (r == (lane & 15)) diagS[w][r] = acc[q];
    }
    __syncthreads();

    float s = 0.f;
    #pragma unroll
    for (int q = 0; q < 4; q++) {
        int r = (lane >> 4) * 4 + q, c = lane & 15;
        if (r != c) {
            float d2 = diagS[w][r] + diagS[w][c] - 2.f * acc[q];
            s += (d2 > 0.f) ? sqrtf(fmaxf(d2, 1e-12f)) : 0.f;
        }
    }
    #pragma unroll
    for (int off = 32; off; off >>= 1) s += __shfl_down(s, off, 64);

    if (lane == 0) {
        float inter_mean = (0.5f * s) / 120.f;
        float avg = row_sum[i] / 16.f;
        float curv = inter_mean / (avg + 1e-8f);
        float diff = curv - ref_curv[i];
        curv_err[i] = diff * diff;
    }
}

// ---------------- kernel 5: final scalar reduce ------------------------------
__global__ __launch_bounds__(1024)
void k_final(const float* __restrict__ curv_err, const float* __restrict__ row_sum,
             const float* __restrict__ ref_dist, float* __restrict__ out) {
    const int t = threadIdx.x;
    float s1 = 0.f, s2 = 0.f, s3 = 0.f;
    for (int i = t; i < N; i += 1024) { s1 += curv_err[i]; s2 += row_sum[i]; }
    for (int i = t; i < N * K; i += 1024) s3 += ref_dist[i];
    for (int off = 32; off; off >>= 1) {
        s1 += __shfl_down(s1, off, 64);
        s2 += __shfl_down(s2, off, 64);
        s3 += __shfl_down(s3, off, 64);
    }
    __shared__ float a1[16], a2[16], a3[16];
    int w = t >> 6, lane = t & 63;
    if (lane == 0) { a1[w] = s1; a2[w] = s2; a3[w] = s3; }
    __syncthreads();
    if (t == 0) {
        float t1 = 0.f, t2 = 0.f, t3 = 0.f;
        for (int q = 0; q < 16; q++) { t1 += a1[q]; t2 += a2[q]; t3 += a3[q]; }
        float curv_loss = t1 / (float)N;
        float dm = t2 / (float)(N * K);
        float rm = t3 / (float)(N * K);
        float d = dm - rm;
        out[0] = curv_loss + 0.1f * d * d;
    }
}

extern "C" void kernel_launch(void* const* d_in, const int* in_sizes, int n_in,
                              void* d_out, int out_size, void* d_ws, size_t ws_size,
                              hipStream_t stream) {
    const float* emb      = (const float*)d_in[0];
    const float* ref_curv = (const float*)d_in[1];
    const float* ref_dist = (const float*)d_in[2];
    float* out = (float*)d_out;

    float*  sq       = (float*)d_ws;                         // N
    float*  row_sum  = sq + N;                               // N
    float*  curv_err = row_sum + N;                          // N
    float*  pd2      = curv_err + N;                         // N*64
    int*    pidx     = (int*)(pd2 + (size_t)N * NSL * K);    // N*64
    int*    knn      = pidx + (size_t)N * NSL * K;           // N*K
    __bf16* embh     = (__bf16*)(knn + (size_t)N * K);       // N*D bf16 (8 MB)

    k_cast_sqnorm<<<N / 4, 256, 0, stream>>>(emb, sq, embh);
    k_knn<<<(N / RB) * NSL, 512, 0, stream>>>(embh, sq, pd2, pidx);
    k_merge<<<N / 256, 256, 0, stream>>>(pd2, pidx, knn, row_sum);
    k_curv<<<N / 4, 256, 0, stream>>>(embh, knn, row_sum, ref_curv, curv_err);
    k_final<<<1, 1024, 0, stream>>>(curv_err, row_sum, ref_dist, out);
}